// Round 1
// baseline (63.384 us; speedup 1.0000x reference)
//
#include <hip/hip_runtime.h>
#include <hip/hip_bf16.h>
#include <stdint.h>

// MNISTQuant: out[65536,50] = x[65536,784] @ (int8_w[784,50] * scaler)
// Memory-bound (205 MB x-read). bf16 MFMA 16x16x32, BM=16 row tiles,
// weights dequantized once into per-wave register B-fragments.

typedef __attribute__((ext_vector_type(8))) short bf16x8;
typedef __attribute__((ext_vector_type(4))) float f32x4;

#define IN_F 784
#define OUT_F 50
#define NSTEP 25          // ceil(784/32) -> K padded to 800
#define BM 16             // rows per tile
#define LDK 808           // LDS row stride in bf16 elems (pad: 404 dwords -> 2-way bank alias = free)
#define TILE_F4 (BM * (IN_F / 4))   // 3136 float4 per tile
#define NTILES 4096       // 65536 / 16
#define TPB_TILES 8       // tiles per block
#define NBLK (NTILES / TPB_TILES)   // 512 = 2 blocks/CU on 256 CUs
#define NTHREADS 256

__device__ __forceinline__ unsigned short f2bf(float f) {
    unsigned int u = __builtin_bit_cast(unsigned int, f);
    u += 0x7FFFu + ((u >> 16) & 1u);   // round-to-nearest-even
    return (unsigned short)(u >> 16);
}

__global__ __launch_bounds__(NTHREADS, 2) void MNISTQuant_48687749267957_kernel(
    const float* __restrict__ x,
    const int* __restrict__ wq,          // int8 weights delivered as int32 per harness
    const float* __restrict__ scaler,
    float* __restrict__ out)
{
    __shared__ union U {
        unsigned short a[2][BM][LDK];    // 2 x 16 x 808 bf16 = 51,712 B (x double-buffer)
        signed char    w8[IN_F * OUT_F]; // 39,200 B raw int8 weights (prologue only)
    } lds;

    const int tid  = threadIdx.x;
    const int lane = tid & 63;
    const int wave = tid >> 6;           // 0..3 -> output col tile

    // ---- Prologue 1: stage raw int8 weights into LDS (coalesced int32 reads) ----
    for (int g = tid; g < (IN_F * OUT_F) / 4; g += NTHREADS) {   // 9800 groups of 4
        const int4 v = *(const int4*)&wq[g * 4];
        unsigned int packed = (v.x & 255) | ((v.y & 255) << 8) |
                              ((v.z & 255) << 16) | (((unsigned int)v.w) << 24);
        *(unsigned int*)&lds.w8[g * 4] = packed;
    }
    __syncthreads();

    // ---- Prologue 2: build per-wave register B-fragments (dequant int8 -> bf16) ----
    const float scl  = scaler[0];
    const int   bcol = wave * 16 + (lane & 15);  // global output col (may be >= 50 -> pad)
    const int   kgrp = (lane >> 4) * 8;          // k sub-chunk within a 32-wide K step
    bf16x8 bfrag[NSTEP];
    #pragma unroll
    for (int s = 0; s < NSTEP; ++s) {
        #pragma unroll
        for (int j = 0; j < 8; ++j) {
            const int k = s * 32 + kgrp + j;
            float w = 0.f;
            if (k < IN_F && bcol < OUT_F)
                w = (float)lds.w8[k * OUT_F + bcol] * scl;
            bfrag[s][j] = (short)f2bf(w);
        }
    }
    __syncthreads();   // done reading w8; LDS now reused for x tiles

    // ---- Prologue 3: zero-fill the K-pad region [784..800) of both buffers ----
    lds.a[0][tid >> 4][IN_F + (tid & 15)] = 0;
    lds.a[1][tid >> 4][IN_F + (tid & 15)] = 0;

    const float4* x4 = (const float4*)x;
    float4 regs[13];   // ceil(3136/256) staging registers

    const int tile0 = blockIdx.x * TPB_TILES;

    // stage tile 0
    {
        const int base = tile0 * TILE_F4;
        #pragma unroll
        for (int u = 0; u < 13; ++u) {
            const int idx = u * NTHREADS + tid;
            if (idx < TILE_F4) regs[u] = x4[base + idx];
        }
        #pragma unroll
        for (int u = 0; u < 13; ++u) {
            const int idx = u * NTHREADS + tid;
            if (idx < TILE_F4) {
                const int row = idx / 196;
                const int c4  = idx - row * 196;
                ushort4 h;
                h.x = f2bf(regs[u].x); h.y = f2bf(regs[u].y);
                h.z = f2bf(regs[u].z); h.w = f2bf(regs[u].w);
                *(ushort4*)&lds.a[0][row][c4 * 4] = h;
            }
        }
    }
    __syncthreads();

    int cur = 0;
    const int arow = lane & 15;
    for (int i = 0; i < TPB_TILES; ++i) {
        const int tile = tile0 + i;

        // (a) issue next tile's global loads early (latency hides under compute)
        if (i + 1 < TPB_TILES) {
            const int base = (tile + 1) * TILE_F4;
            #pragma unroll
            for (int u = 0; u < 13; ++u) {
                const int idx = u * NTHREADS + tid;
                if (idx < TILE_F4) regs[u] = x4[base + idx];
            }
        }

        // (b) compute current tile: 25 x (ds_read_b128 + MFMA)
        f32x4 acc = {0.f, 0.f, 0.f, 0.f};
        #pragma unroll
        for (int s = 0; s < NSTEP; ++s) {
            bf16x8 a = *(const bf16x8*)&lds.a[cur][arow][s * 32 + kgrp];
            acc = __builtin_amdgcn_mfma_f32_16x16x32_bf16(a, bfrag[s], acc, 0, 0, 0);
        }

        // (c) store C: col = lane&15 (+wave*16), rows = (lane>>4)*4 + j  [verified m89 layout]
        if (bcol < OUT_F) {
            const int r0 = tile * BM + (lane >> 4) * 4;
            #pragma unroll
            for (int j = 0; j < 4; ++j)
                out[(r0 + j) * OUT_F + bcol] = acc[j];
        }

        // (d) write next tile into the other buffer (compiler inserts vmcnt wait)
        if (i + 1 < TPB_TILES) {
            #pragma unroll
            for (int u = 0; u < 13; ++u) {
                const int idx = u * NTHREADS + tid;
                if (idx < TILE_F4) {
                    const int row = idx / 196;
                    const int c4  = idx - row * 196;
                    ushort4 h;
                    h.x = f2bf(regs[u].x); h.y = f2bf(regs[u].y);
                    h.z = f2bf(regs[u].z); h.w = f2bf(regs[u].w);
                    *(ushort4*)&lds.a[cur ^ 1][row][c4 * 4] = h;
                }
            }
        }
        __syncthreads();
        cur ^= 1;
    }
}

extern "C" void kernel_launch(void* const* d_in, const int* in_sizes, int n_in,
                              void* d_out, int out_size, void* d_ws, size_t ws_size,
                              hipStream_t stream) {
    const float* x      = (const float*)d_in[0];
    const int*   wq     = (const int*)d_in[1];
    const float* scaler = (const float*)d_in[2];
    float*       out    = (float*)d_out;
    MNISTQuant_48687749267957_kernel<<<NBLK, NTHREADS, 0, stream>>>(x, wq, scaler, out);
}